// Round 10
// baseline (186.831 us; speedup 1.0000x reference)
//
#include <hip/hip_runtime.h>
#include <hip/hip_bf16.h>

// Problem constants
#define BATCH 2
#define SLEN 2048
#define DMODEL 1024
#define NHEADS 16
#define NKV 4
#define DHEAD 64
#define WINDOW 256
#define NGLOBAL 4

typedef __attribute__((ext_vector_type(8))) short short8;
typedef __attribute__((ext_vector_type(4))) float floatx4;

__device__ __forceinline__ ushort f2bf(float f) {
    __hip_bfloat16 h = __float2bfloat16(f);
    return *reinterpret_cast<ushort*>(&h);
}
__device__ __forceinline__ float bf2f(ushort u) {
    __hip_bfloat16 h = *reinterpret_cast<__hip_bfloat16*>(&u);
    return __bfloat162float(h);
}
// dtype flag: cos[0]==1.0f exactly. fp32 -> low16 of first dword == 0x0000;
// bf16 pair -> low16 == 0x3F80. Wave-uniform, graph-capture safe.
__device__ __forceinline__ bool is_bf16_inputs(const uint* cosu) {
    return (cosu[0] & 0xFFFFu) != 0u;
}
// async global->LDS, 16B per lane. LDS dest is wave-uniform base + lane*16.
__device__ __forceinline__ void gload_lds16(const ushort* g, ushort* l) {
    __builtin_amdgcn_global_load_lds(
        (const __attribute__((address_space(1))) void*)g,
        (__attribute__((address_space(3))) void*)l, 16, 0, 0);
}

// Padded-row staging map: LDS rows of 64 data ushorts padded to 72 (144 B = 9x16B).
// 16B chunk c2 -> srow = c2/9, col = (c2%9)*8; rem==8 lands in the pad (reload col 0).
// Row stride 36 dwords => fragment ds_read_b128 <=2-way bank aliasing (free, m136).
__device__ __forceinline__ void stage_row(const ushort* gbase, size_t gstride, int k0,
                                          ushort* lds, int call, int lane) {
    const int c2 = call * 64 + lane;
    const int srow = c2 / 9;
    const int rem = c2 - srow * 9;
    const int colu = (rem == 8) ? 0 : rem * 8;
    gload_lds16(&gbase[(size_t)srow * gstride + k0 + colu], &lds[call * 512]);
}

// In-LDS transposed W staging: thread loads W[k0+lane][cn + ncol .. +7] (native [k][n]),
// scatters 8 ds_write_b16 into lsB[(ncol+i)*72 + lane]. Writes hit dword
// (ncol+i)*36 + lane/2 -> all 32 banks, 2 lanes/dword (merged) => conflict-free.
__device__ __forceinline__ void stage_wT(const void* W, bool isbf, int N, int cn,
                                         int k0, int ncol, int lane, ushort* lsB) {
    ushort v[8];
    if (isbf) {
        const ushort* Ws = reinterpret_cast<const ushort*>(W);
        uint4 raw = *reinterpret_cast<const uint4*>(&Ws[(size_t)(k0 + lane) * N + cn + ncol]);
        *reinterpret_cast<uint4*>(v) = raw;
    } else {
        const float* Wf = reinterpret_cast<const float*>(W);
        const float* p = &Wf[(size_t)(k0 + lane) * N + cn + ncol];
#pragma unroll
        for (int i = 0; i < 8; ++i) v[i] = f2bf(p[i]);
    }
#pragma unroll
    for (int i = 0; i < 8; ++i) lsB[(ncol + i) * 72 + lane] = v[i];
}

// ---------------- QKV GEMM (128M x 64N head-slot tiles) + fused norm/RoPE epilogue ----
// Reads x and Wq/Wk/Wv natively (no prep dispatch): A async-staged (bf16) or cvt-staged
// (f32); B transposed in-LDS at stage time. Epilogue: l2norm + RoPE -> Qb/Kg, V -> Vtg^T.
__global__ __launch_bounds__(256) void gemm_qkv_nr(const void* __restrict__ x,
                                                   const void* __restrict__ cosi,
                                                   const void* __restrict__ sini,
                                                   const void* __restrict__ Wq,
                                                   const void* __restrict__ Wk,
                                                   const void* __restrict__ Wv,
                                                   ushort* __restrict__ Qb,
                                                   ushort* __restrict__ Kg,
                                                   ushort* __restrict__ Vtg,
                                                   const uint* __restrict__ cosu)
{
    __shared__ __align__(16) ushort sm[13824];    // lsA 128x72 | lsB 64x72 = 27648 B
    ushort* lsA = sm;
    ushort* lsB = sm + 9216;
    const int tid = threadIdx.x;
    const int lane = tid & 63, w = tid >> 6;
    const int ln15 = lane & 15, quad = lane >> 4;
    const int z = blockIdx.x;                     // head-slot 0..23
    const int rm = blockIdx.y * 128;
    const bool isbf = is_bf16_inputs(cosu);

    const void* Wsrc; int N, cn;
    if (z < 16)      { Wsrc = Wq; N = 1024; cn = z * 64; }
    else if (z < 20) { Wsrc = Wk; N = 256;  cn = (z - 16) * 64; }
    else             { Wsrc = Wv; N = 256;  cn = (z - 20) * 64; }

    floatx4 acc[2][4];
#pragma unroll
    for (int i = 0; i < 2; ++i)
#pragma unroll
        for (int j = 0; j < 4; ++j) acc[i][j] = (floatx4){0.f, 0.f, 0.f, 0.f};

    const ushort* xb16 = reinterpret_cast<const ushort*>(x) + (size_t)rm * 1024;
    const float* xf32 = reinterpret_cast<const float*>(x) + (size_t)rm * 1024;

    for (int k0 = 0; k0 < 1024; k0 += 64) {
        __syncthreads();
        if (isbf) {
#pragma unroll
            for (int i = 0; i < 5; ++i) {         // A: 128 rows -> 18 async calls
                const int call = i * 4 + w;
                if (call < 18) stage_row(xb16, 1024, k0, lsA, call, lane);
            }
        } else {
#pragma unroll
            for (int j = 0; j < 4; ++j) {         // f32 fallback: cvt + b128 write
                const int c = tid + j * 256;
                const int srow = c >> 3, col = (c & 7) * 8;
                const float* p = &xf32[(size_t)srow * 1024 + k0 + col];
                ushort o[8];
#pragma unroll
                for (int i = 0; i < 8; ++i) o[i] = f2bf(p[i]);
                *reinterpret_cast<uint4*>(&lsA[srow * 72 + col]) = *reinterpret_cast<uint4*>(o);
            }
        }
        stage_wT(Wsrc, isbf, N, cn, k0, w * 8, lane, lsB);        // B: 2 col-groups/thread
        stage_wT(Wsrc, isbf, N, cn, k0, (w + 4) * 8, lane, lsB);
        __syncthreads();
#pragma unroll
        for (int kk = 0; kk < 64; kk += 32) {
            short8 af[2], bv[4];
#pragma unroll
            for (int i = 0; i < 2; ++i)
                af[i] = *reinterpret_cast<const short8*>(&lsA[(w * 32 + i * 16 + ln15) * 72 + kk + quad * 8]);
#pragma unroll
            for (int j = 0; j < 4; ++j)
                bv[j] = *reinterpret_cast<const short8*>(&lsB[(j * 16 + ln15) * 72 + kk + quad * 8]);
#pragma unroll
            for (int i = 0; i < 2; ++i)
#pragma unroll
                for (int j = 0; j < 4; ++j)
                    acc[i][j] = __builtin_amdgcn_mfma_f32_16x16x32_bf16(af[i], bv[j], acc[i][j], 0, 0, 0);
        }
    }

    __syncthreads();
    const int b = rm >> 11, s0 = rm & (SLEN - 1);
    if (z < 20) {
        // Q/K: l2norm + rope -> staged [128][72] -> coalesced store
        const ushort* cosb = reinterpret_cast<const ushort*>(cosi);
        const ushort* sinb = reinterpret_cast<const ushort*>(sini);
        const float* cosF = reinterpret_cast<const float*>(cosi);
        const float* sinF = reinterpret_cast<const float*>(sini);
#pragma unroll
        for (int i = 0; i < 2; ++i) {
#pragma unroll
            for (int r = 0; r < 4; ++r) {
                const int row_l = w * 32 + i * 16 + quad * 4 + r;
                float v0 = acc[i][0][r], v1 = acc[i][1][r], v2 = acc[i][2][r], v3 = acc[i][3][r];
                float ss = v0 * v0 + v1 * v1 + v2 * v2 + v3 * v3;
                ss += __shfl_xor(ss, 1, 64);
                ss += __shfl_xor(ss, 2, 64);
                ss += __shfl_xor(ss, 4, 64);
                ss += __shfl_xor(ss, 8, 64);
                const float inv = 1.f / (sqrtf(ss) + 1e-8f);
                const float n0 = v0 * inv, n1 = v1 * inv, n2 = v2 * inv, n3 = v3 * inv;
                const int spos = s0 + row_l;
                float c0, c1, sn0, sn1;
                if (isbf) {
                    c0 = bf2f(cosb[spos * 32 + ln15]);  c1 = bf2f(cosb[spos * 32 + 16 + ln15]);
                    sn0 = bf2f(sinb[spos * 32 + ln15]); sn1 = bf2f(sinb[spos * 32 + 16 + ln15]);
                } else {
                    c0 = cosF[spos * 32 + ln15];  c1 = cosF[spos * 32 + 16 + ln15];
                    sn0 = sinF[spos * 32 + ln15]; sn1 = sinF[spos * 32 + 16 + ln15];
                }
                sm[row_l * 72 + ln15]      = f2bf(n0 * c0 - n2 * sn0);
                sm[row_l * 72 + 16 + ln15] = f2bf(n1 * c1 - n3 * sn1);
                sm[row_l * 72 + 32 + ln15] = f2bf(n0 * sn0 + n2 * c0);
                sm[row_l * 72 + 48 + ln15] = f2bf(n1 * sn1 + n3 * c1);
            }
        }
        __syncthreads();
        ushort* dst = (z < 16) ? Qb + ((size_t)(b * NHEADS + z) * SLEN + s0) * 64
                               : Kg + ((size_t)(b * NKV + (z - 16)) * SLEN + s0) * 64;
#pragma unroll
        for (int it = 0; it < 4; ++it) {
            const int c = it * 256 + tid;
            const int row = c >> 3, col = (c & 7) * 8;
            *reinterpret_cast<uint4*>(dst + (size_t)row * 64 + col) =
                *reinterpret_cast<const uint4*>(&sm[row * 72 + col]);
        }
    } else {
        // V: bf16, LDS-transposed [64 d][136] -> coalesced Vtg rows [d][2048]
#pragma unroll
        for (int i = 0; i < 2; ++i)
#pragma unroll
            for (int r = 0; r < 4; ++r) {
                const int row_l = w * 32 + i * 16 + quad * 4 + r;
#pragma unroll
                for (int j = 0; j < 4; ++j)
                    sm[(j * 16 + ln15) * 136 + row_l] = f2bf(acc[i][j][r]);
            }
        __syncthreads();
        ushort* dst = Vtg + ((size_t)(b * NKV + (z - 20)) * 64) * SLEN;
#pragma unroll
        for (int it = 0; it < 4; ++it) {
            const int c = it * 256 + tid;
            const int d = c >> 4, sb = (c & 15) * 8;
            *reinterpret_cast<uint4*>(dst + (size_t)d * SLEN + s0 + sb) =
                *reinterpret_cast<const uint4*>(&sm[d * 136 + sb]);
        }
    }
}

// ---------------- MFMA windowed flash attention, 64-key chunks, async staging ----------
// No running max: q,k unit vectors => |score*scale| <= 0.125, exp safe.
// softcap via Taylor: 15*tanh(sv/15) = sv - sv^3/675 (err ~8e-11 at |sv|<=0.125).
// Interior chunks (all 64 keys valid for the wave's 16 queries) skip mask predicates.
__global__ __launch_bounds__(256) void attn_mfma(const ushort* __restrict__ Qb,
                                                 const ushort* __restrict__ Kg,
                                                 const ushort* __restrict__ Vtg,
                                                 ushort* __restrict__ ctx)
{
    __shared__ __align__(16) ushort sm[13824];
    ushort* Ks = sm;                   // [64 keys][72]
    ushort* Vs = sm + 4608;            // [64 dims][72]
    const int tid = threadIdx.x;
    const int lane = tid & 63, w = tid >> 6;
    const int ln15 = lane & 15, quad = lane >> 4;
    ushort* Ps = sm + 9216 + w * 1152; // per-wave [16 q][72]
    const int bid = blockIdx.x;
    const int qt = bid & 31, bh = bid >> 5;
    const int h = bh & (NHEADS - 1), b = bh >> 4, hkv = h >> 2;
    const int q0 = qt * 64;
    const int qw = q0 + w * 16;

    const ushort* Qrow = Qb + ((size_t)bh * SLEN + qw) * 64;
    const ushort* Kbase = Kg + (size_t)(b * NKV + hkv) * SLEN * 64;
    const ushort* Vbase = Vtg + (size_t)(b * NKV + hkv) * 64 * SLEN;

    short8 qf0 = *reinterpret_cast<const short8*>(Qrow + (size_t)ln15 * 64 + quad * 8);
    short8 qf1 = *reinterpret_cast<const short8*>(Qrow + (size_t)ln15 * 64 + 32 + quad * 8);

    floatx4 O0 = {0,0,0,0}, O1 = {0,0,0,0}, O2 = {0,0,0,0}, O3 = {0,0,0,0};
    float lp[4] = {0.f, 0.f, 0.f, 0.f};

    int kminA = q0 - (WINDOW - 1); if (kminA < 0) kminA = 0;
    kminA &= ~63;
    const int gmax = kminA < NGLOBAL ? kminA : NGLOBAL;
    const int nc = (q0 + 64 - kminA) >> 6;

    for (int c = (gmax > 0 ? -1 : 0); c < nc; ++c) {
        const int kbase = (c < 0) ? 0 : kminA + c * 64;
        __syncthreads();
#pragma unroll
        for (int i = 0; i < 3; ++i) {             // K: 64 rows -> 9 async calls
            const int call = i * 4 + w;
            if (call < 9) stage_row(Kbase + (size_t)kbase * 64, 64, 0, Ks, call, lane);
        }
#pragma unroll
        for (int i = 0; i < 3; ++i) {             // V^T: 64 rows -> 9 async calls
            const int call = i * 4 + w;
            if (call < 9) stage_row(Vbase + kbase, SLEN, 0, Vs, call, lane);
        }
        __syncthreads();

        const bool allvalid = (c >= 0) && (kbase + 63 <= qw) && (kbase + WINDOW >= qw + 16);
        if (allvalid) {
#pragma unroll
            for (int t = 0; t < 4; ++t) {
                short8 kf0 = *reinterpret_cast<const short8*>(&Ks[(t * 16 + ln15) * 72 + quad * 8]);
                short8 kf1 = *reinterpret_cast<const short8*>(&Ks[(t * 16 + ln15) * 72 + 32 + quad * 8]);
                floatx4 sc = {0,0,0,0};
                sc = __builtin_amdgcn_mfma_f32_16x16x32_bf16(qf0, kf0, sc, 0, 0, 0);
                sc = __builtin_amdgcn_mfma_f32_16x16x32_bf16(qf1, kf1, sc, 0, 0, 0);
#pragma unroll
                for (int r = 0; r < 4; ++r) {
                    float sv = sc[r] * 0.125f;
                    float st = sv - sv * sv * sv * (1.0f / 675.0f);
                    float p = __expf(st);
                    Ps[(quad * 4 + r) * 72 + t * 16 + ln15] = f2bf(p);
                    lp[r] += p;
                }
            }
        } else {
#pragma unroll
            for (int t = 0; t < 4; ++t) {
                short8 kf0 = *reinterpret_cast<const short8*>(&Ks[(t * 16 + ln15) * 72 + quad * 8]);
                short8 kf1 = *reinterpret_cast<const short8*>(&Ks[(t * 16 + ln15) * 72 + 32 + quad * 8]);
                floatx4 sc = {0,0,0,0};
                sc = __builtin_amdgcn_mfma_f32_16x16x32_bf16(qf0, kf0, sc, 0, 0, 0);
                sc = __builtin_amdgcn_mfma_f32_16x16x32_bf16(qf1, kf1, sc, 0, 0, 0);
                const int k = kbase + t * 16 + ln15;
#pragma unroll
                for (int r = 0; r < 4; ++r) {
                    const int q = qw + quad * 4 + r;
                    const bool valid = (c < 0) ? (k < gmax)
                                               : (k <= q && (k + WINDOW > q || k < NGLOBAL));
                    float sv = sc[r] * 0.125f;
                    float st = sv - sv * sv * sv * (1.0f / 675.0f);
                    float p = __expf(st);
                    Ps[(quad * 4 + r) * 72 + t * 16 + ln15] = valid ? f2bf(p) : (ushort)0;
                    lp[r] += valid ? p : 0.f;
                }
            }
        }
        short8 af0 = *reinterpret_cast<const short8*>(&Ps[ln15 * 72 + quad * 8]);
        short8 af1 = *reinterpret_cast<const short8*>(&Ps[ln15 * 72 + 32 + quad * 8]);
#pragma unroll
        for (int n = 0; n < 4; ++n) {
            short8 vf0 = *reinterpret_cast<const short8*>(&Vs[(n * 16 + ln15) * 72 + quad * 8]);
            short8 vf1 = *reinterpret_cast<const short8*>(&Vs[(n * 16 + ln15) * 72 + 32 + quad * 8]);
            floatx4 On = (n == 0) ? O0 : (n == 1) ? O1 : (n == 2) ? O2 : O3;
            On = __builtin_amdgcn_mfma_f32_16x16x32_bf16(af0, vf0, On, 0, 0, 0);
            On = __builtin_amdgcn_mfma_f32_16x16x32_bf16(af1, vf1, On, 0, 0, 0);
            if (n == 0) O0 = On; else if (n == 1) O1 = On; else if (n == 2) O2 = On; else O3 = On;
        }
    }

#pragma unroll
    for (int r = 0; r < 4; ++r) {
#pragma unroll
        for (int off = 1; off < 16; off <<= 1)
            lp[r] += __shfl_xor(lp[r], off, 64);
        const float inv = __builtin_amdgcn_rcpf(lp[r]);
        const int q = qw + quad * 4 + r;
        ushort* crow = ctx + ((size_t)(b * SLEN + q)) * DMODEL + h * 64 + ln15;
        crow[0]  = f2bf(O0[r] * inv);
        crow[16] = f2bf(O1[r] * inv);
        crow[32] = f2bf(O2[r] * inv);
        crow[48] = f2bf(O3[r] * inv);
    }
}

// ---------------- out-proj GEMM: 128M x 64N tile, native Wo (in-LDS transpose) ----------
__global__ __launch_bounds__(256) void gemm_out(const ushort* __restrict__ A,
                                                const void* __restrict__ Wo,
                                                void* __restrict__ out,
                                                const uint* __restrict__ cosu)
{
    __shared__ __align__(16) ushort sm[13824];
    ushort* lsA = sm;            // 128 x 72
    ushort* lsB = sm + 9216;     // 64 x 72
    const int tid = threadIdx.x;
    const int lane = tid & 63, w = tid >> 6;
    const int ln15 = lane & 15, quad = lane >> 4;
    const int rm = blockIdx.y * 128;
    const int cn = blockIdx.x * 64;
    const bool isbf = is_bf16_inputs(cosu);

    floatx4 acc[2][4];
#pragma unroll
    for (int i = 0; i < 2; ++i)
#pragma unroll
        for (int j = 0; j < 4; ++j) acc[i][j] = (floatx4){0.f, 0.f, 0.f, 0.f};

    const ushort* Ab = A + (size_t)rm * 1024;

    for (int k0 = 0; k0 < 1024; k0 += 64) {
        __syncthreads();
#pragma unroll
        for (int i = 0; i < 5; ++i) {             // A (ctx, always bf16): 18 async calls
            const int call = i * 4 + w;
            if (call < 18) stage_row(Ab, 1024, k0, lsA, call, lane);
        }
        stage_wT(Wo, isbf, 1024, cn, k0, w * 8, lane, lsB);
        stage_wT(Wo, isbf, 1024, cn, k0, (w + 4) * 8, lane, lsB);
        __syncthreads();
#pragma unroll
        for (int kk = 0; kk < 64; kk += 32) {
            short8 af[2], bv[4];
#pragma unroll
            for (int i = 0; i < 2; ++i)
                af[i] = *reinterpret_cast<const short8*>(&lsA[(w * 32 + i * 16 + ln15) * 72 + kk + quad * 8]);
#pragma unroll
            for (int j = 0; j < 4; ++j)
                bv[j] = *reinterpret_cast<const short8*>(&lsB[(j * 16 + ln15) * 72 + kk + quad * 8]);
#pragma unroll
            for (int i = 0; i < 2; ++i)
#pragma unroll
                for (int j = 0; j < 4; ++j)
                    acc[i][j] = __builtin_amdgcn_mfma_f32_16x16x32_bf16(af[i], bv[j], acc[i][j], 0, 0, 0);
        }
    }

#pragma unroll
    for (int i = 0; i < 2; ++i) {
#pragma unroll
        for (int r = 0; r < 4; ++r) {
            const int grow = rm + w * 32 + i * 16 + quad * 4 + r;
#pragma unroll
            for (int j = 0; j < 4; ++j) {
                const int gcol = cn + j * 16 + ln15;
                if (isbf) reinterpret_cast<ushort*>(out)[(size_t)grow * DMODEL + gcol] = f2bf(acc[i][j][r]);
                else      reinterpret_cast<float*>(out)[(size_t)grow * DMODEL + gcol] = acc[i][j][r];
            }
        }
    }
}

// ---------------- launch: 3 dispatches ----------------
extern "C" void kernel_launch(void* const* d_in, const int* in_sizes, int n_in,
                              void* d_out, int out_size, void* d_ws, size_t ws_size,
                              hipStream_t stream)
{
    (void)in_sizes; (void)n_in; (void)out_size; (void)ws_size;
    const void* x = d_in[0];
    const void* cosi = d_in[1];
    const void* sini = d_in[2];
    const uint* cosu = (const uint*)d_in[1];
    // d_in[3] = mask: computed analytically, not read
    const void* Wq = d_in[4];
    const void* Wk = d_in[5];
    const void* Wv = d_in[6];
    const void* Wo = d_in[7];

    // workspace (~12.6 MB)
    ushort* Qbf = (ushort*)d_ws;                               // [2*16*2048][64] bf16
    ushort* Kgf = Qbf + (size_t)BATCH * NHEADS * SLEN * 64;    // [2*4*2048][64]
    ushort* Vtg = Kgf + (size_t)BATCH * NKV * SLEN * 64;       // [2*4][64][2048]
    ushort* ctx = Vtg + (size_t)BATCH * NKV * 64 * SLEN;       // [4096][1024]

    // 1) QKV projection from native inputs + fused l2norm/RoPE/relayout (768 blocks)
    gemm_qkv_nr<<<dim3(24, 32), 256, 0, stream>>>(x, cosi, sini, Wq, Wk, Wv,
                                                  Qbf, Kgf, Vtg, cosu);

    // 2) MFMA windowed attention (1024 blocks)
    attn_mfma<<<dim3(BATCH * NHEADS * SLEN / 64), 256, 0, stream>>>(Qbf, Kgf, Vtg, ctx);

    // 3) output projection from native Wo -> d_out (512 blocks, dtype-matched)
    gemm_out<<<dim3(16, 32), 256, 0, stream>>>(ctx, Wo, d_out, cosu);
}

// Round 11
// 154.112 us; speedup vs baseline: 1.2123x; 1.2123x over previous
//
#include <hip/hip_runtime.h>
#include <hip/hip_bf16.h>

// Problem constants
#define BATCH 2
#define SLEN 2048
#define DMODEL 1024
#define NHEADS 16
#define NKV 4
#define DHEAD 64
#define WINDOW 256
#define NGLOBAL 4

typedef __attribute__((ext_vector_type(8))) short short8;
typedef __attribute__((ext_vector_type(4))) float floatx4;

__device__ __forceinline__ ushort f2bf(float f) {
    __hip_bfloat16 h = __float2bfloat16(f);
    return *reinterpret_cast<ushort*>(&h);
}
__device__ __forceinline__ float bf2f(ushort u) {
    __hip_bfloat16 h = *reinterpret_cast<__hip_bfloat16*>(&u);
    return __bfloat162float(h);
}
// dtype flag: cos[0]==1.0f exactly. fp32 -> low16 of first dword == 0x0000;
// bf16 pair -> low16 == 0x3F80. Wave-uniform, graph-capture safe.
__device__ __forceinline__ bool is_bf16_inputs(const uint* cosu) {
    return (cosu[0] & 0xFFFFu) != 0u;
}
// async global->LDS, 16B per lane. LDS dest is wave-uniform base + lane*16.
__device__ __forceinline__ void gload_lds16(const ushort* g, ushort* l) {
    __builtin_amdgcn_global_load_lds(
        (const __attribute__((address_space(1))) void*)g,
        (__attribute__((address_space(3))) void*)l, 16, 0, 0);
}

// Padded-row staging map: LDS rows of 64 data ushorts padded to 72 (144 B = 9x16B).
// 16B chunk c2 -> srow = c2/9, col = (c2%9)*8; rem==8 lands in the pad (reload col 0).
// Row stride 36 dwords => fragment ds_read_b128 <=2-way bank aliasing (free, m136).
__device__ __forceinline__ void stage_row(const ushort* gbase, size_t gstride, int k0,
                                          ushort* lds, int call, int lane) {
    const int c2 = call * 64 + lane;
    const int srow = c2 / 9;
    const int rem = c2 - srow * 9;
    const int colu = (rem == 8) ? 0 : rem * 8;
    gload_lds16(&gbase[(size_t)srow * gstride + k0 + colu], &lds[call * 512]);
}

// ---------------- prep: canonicalize (f32 case only) + transpose all weights ----------
// R10 lesson: strided in-GEMM weight transpose wastes 4x HBM (16B used / 64B line) per
// consumer block. One coalesced transpose pass here is cheaper. bf16 x needs no copy
// (consumers read it directly); those blocks exit immediately.
__global__ __launch_bounds__(256) void prep_all(const void* __restrict__ x,
                                                const void* __restrict__ cosi,
                                                const void* __restrict__ sini,
                                                const void* __restrict__ Wq,
                                                const void* __restrict__ Wk,
                                                const void* __restrict__ Wv,
                                                const void* __restrict__ Wo,
                                                ushort* __restrict__ xb,
                                                float* __restrict__ cosf,
                                                float* __restrict__ sinf,
                                                ushort* __restrict__ Wt,
                                                ushort* __restrict__ Wot,
                                                const uint* __restrict__ cosu)
{
    __shared__ ushort t[32][33];
    const bool isbf = is_bf16_inputs(cosu);
    const int bid = blockIdx.x, tid = threadIdx.x;
    if (bid < 2048) {
        if (isbf) return;                          // xb unused: consumers read x directly
        size_t i = (size_t)bid * 256 + tid;
        size_t e = i * 8;
        const float* f = reinterpret_cast<const float*>(x) + e;
        ushort o[8];
#pragma unroll
        for (int j = 0; j < 8; ++j) o[j] = f2bf(f[j]);
        *reinterpret_cast<uint4*>(xb + e) = *reinterpret_cast<uint4*>(o);
        return;
    }
    if (bid < 2560) {
        int i = (bid - 2048) * 256 + tid;
        const void* src = (i < SLEN * 32) ? cosi : sini;
        float* dst = (i < SLEN * 32) ? cosf : sinf;
        int e = i & (SLEN * 32 - 1);
        dst[e] = isbf ? bf2f(reinterpret_cast<const ushort*>(src)[e])
                      : reinterpret_cast<const float*>(src)[e];
        return;
    }
    const void* src; ushort* dst; int C, tl;
    if (bid < 3584)      { src = Wq; dst = Wt;                       C = 1024; tl = bid - 2560; }
    else if (bid < 3840) { src = Wk; dst = Wt + (size_t)1024 * 1024; C = 256;  tl = bid - 3584; }
    else if (bid < 4096) { src = Wv; dst = Wt + (size_t)1280 * 1024; C = 256;  tl = bid - 3840; }
    else                 { src = Wo; dst = Wot;                      C = 1024; tl = bid - 4096; }
    const int nbx = C >> 5;
    const int bx = (tl % nbx) * 32, by = (tl / nbx) * 32;
    const int tx = tid & 31, ty = tid >> 5;
#pragma unroll
    for (int j = 0; j < 32; j += 8) {
        size_t idx = (size_t)(by + ty + j) * C + bx + tx;
        t[ty + j][tx] = isbf ? reinterpret_cast<const ushort*>(src)[idx]
                             : f2bf(reinterpret_cast<const float*>(src)[idx]);
    }
    __syncthreads();
#pragma unroll
    for (int j = 0; j < 32; j += 8)
        dst[(size_t)(bx + ty + j) * 1024 + by + tx] = t[tx][ty + j];
}

// ---------------- QKV GEMM (128M x 64N head-slot tiles) + fused norm/RoPE epilogue ----
// A staged from x directly (bf16) or from prep's xb (f32 case). B = prep's K-major Wt.
// Padded-72 LDS rows: fragment b128 reads <=2-way bank aliasing.
__global__ __launch_bounds__(256) void gemm_qkv_nr(const void* __restrict__ x,
                                                   const ushort* __restrict__ xb,
                                                   const ushort* __restrict__ Bt,
                                                   const float* __restrict__ cosf,
                                                   const float* __restrict__ sinf,
                                                   ushort* __restrict__ Qb,
                                                   ushort* __restrict__ Kg,
                                                   ushort* __restrict__ Vtg,
                                                   const uint* __restrict__ cosu)
{
    __shared__ __align__(16) ushort sm[13824];    // lsA 128x72 | lsB 64x72 = 27648 B
    ushort* lsA = sm;
    ushort* lsB = sm + 9216;
    const int tid = threadIdx.x;
    const int lane = tid & 63, w = tid >> 6;
    const int ln15 = lane & 15, quad = lane >> 4;
    const int z = blockIdx.x;                     // head-slot 0..23
    const int rm = blockIdx.y * 128;
    const int cn = z * 64;
    const bool isbf = is_bf16_inputs(cosu);

    floatx4 acc[2][4];
#pragma unroll
    for (int i = 0; i < 2; ++i)
#pragma unroll
        for (int j = 0; j < 4; ++j) acc[i][j] = (floatx4){0.f, 0.f, 0.f, 0.f};

    const ushort* Ab = (isbf ? reinterpret_cast<const ushort*>(x) : xb) + (size_t)rm * 1024;
    const ushort* Bb = Bt + (size_t)cn * 1024;

    for (int k0 = 0; k0 < 1024; k0 += 64) {
        __syncthreads();
#pragma unroll
        for (int i = 0; i < 5; ++i) {             // A: 128 rows -> 18 async calls
            const int call = i * 4 + w;
            if (call < 18) stage_row(Ab, 1024, k0, lsA, call, lane);
        }
#pragma unroll
        for (int i = 0; i < 3; ++i) {             // B: 64 rows -> 9 async calls
            const int call = i * 4 + w;
            if (call < 9) stage_row(Bb, 1024, k0, lsB, call, lane);
        }
        __syncthreads();
#pragma unroll
        for (int kk = 0; kk < 64; kk += 32) {
            short8 af[2], bv[4];
#pragma unroll
            for (int i = 0; i < 2; ++i)
                af[i] = *reinterpret_cast<const short8*>(&lsA[(w * 32 + i * 16 + ln15) * 72 + kk + quad * 8]);
#pragma unroll
            for (int j = 0; j < 4; ++j)
                bv[j] = *reinterpret_cast<const short8*>(&lsB[(j * 16 + ln15) * 72 + kk + quad * 8]);
#pragma unroll
            for (int i = 0; i < 2; ++i)
#pragma unroll
                for (int j = 0; j < 4; ++j)
                    acc[i][j] = __builtin_amdgcn_mfma_f32_16x16x32_bf16(af[i], bv[j], acc[i][j], 0, 0, 0);
        }
    }

    __syncthreads();
    const int b = rm >> 11, s0 = rm & (SLEN - 1);
    if (z < 20) {
        // Q/K: l2norm + rope -> staged [128][72] -> coalesced store
#pragma unroll
        for (int i = 0; i < 2; ++i) {
#pragma unroll
            for (int r = 0; r < 4; ++r) {
                const int row_l = w * 32 + i * 16 + quad * 4 + r;
                float v0 = acc[i][0][r], v1 = acc[i][1][r], v2 = acc[i][2][r], v3 = acc[i][3][r];
                float ss = v0 * v0 + v1 * v1 + v2 * v2 + v3 * v3;
                ss += __shfl_xor(ss, 1, 64);
                ss += __shfl_xor(ss, 2, 64);
                ss += __shfl_xor(ss, 4, 64);
                ss += __shfl_xor(ss, 8, 64);
                const float inv = 1.f / (sqrtf(ss) + 1e-8f);
                const float n0 = v0 * inv, n1 = v1 * inv, n2 = v2 * inv, n3 = v3 * inv;
                const int spos = s0 + row_l;
                const float c0 = cosf[spos * 32 + ln15],  c1 = cosf[spos * 32 + 16 + ln15];
                const float sn0 = sinf[spos * 32 + ln15], sn1 = sinf[spos * 32 + 16 + ln15];
                sm[row_l * 72 + ln15]      = f2bf(n0 * c0 - n2 * sn0);
                sm[row_l * 72 + 16 + ln15] = f2bf(n1 * c1 - n3 * sn1);
                sm[row_l * 72 + 32 + ln15] = f2bf(n0 * sn0 + n2 * c0);
                sm[row_l * 72 + 48 + ln15] = f2bf(n1 * sn1 + n3 * c1);
            }
        }
        __syncthreads();
        ushort* dst = (z < 16) ? Qb + ((size_t)(b * NHEADS + z) * SLEN + s0) * 64
                               : Kg + ((size_t)(b * NKV + (z - 16)) * SLEN + s0) * 64;
#pragma unroll
        for (int it = 0; it < 4; ++it) {
            const int c = it * 256 + tid;
            const int row = c >> 3, col = (c & 7) * 8;
            *reinterpret_cast<uint4*>(dst + (size_t)row * 64 + col) =
                *reinterpret_cast<const uint4*>(&sm[row * 72 + col]);
        }
    } else {
        // V: bf16, LDS-transposed [64 d][136] -> coalesced Vtg rows [d][2048]
#pragma unroll
        for (int i = 0; i < 2; ++i)
#pragma unroll
            for (int r = 0; r < 4; ++r) {
                const int row_l = w * 32 + i * 16 + quad * 4 + r;
#pragma unroll
                for (int j = 0; j < 4; ++j)
                    sm[(j * 16 + ln15) * 136 + row_l] = f2bf(acc[i][j][r]);
            }
        __syncthreads();
        ushort* dst = Vtg + ((size_t)(b * NKV + (z - 20)) * 64) * SLEN;
#pragma unroll
        for (int it = 0; it < 4; ++it) {
            const int c = it * 256 + tid;
            const int d = c >> 4, sb = (c & 15) * 8;
            *reinterpret_cast<uint4*>(dst + (size_t)d * SLEN + s0 + sb) =
                *reinterpret_cast<const uint4*>(&sm[d * 136 + sb]);
        }
    }
}

// ---------------- MFMA windowed flash attention, 64-key chunks, async staging ----------
// No running max: q,k unit vectors => |score*scale| <= 0.125, exp safe.
// softcap via Taylor: 15*tanh(sv/15) = sv - sv^3/675 (err ~8e-11 at |sv|<=0.125).
// Interior chunks (all 64 keys valid for the wave's 16 queries) skip mask predicates.
__global__ __launch_bounds__(256) void attn_mfma(const ushort* __restrict__ Qb,
                                                 const ushort* __restrict__ Kg,
                                                 const ushort* __restrict__ Vtg,
                                                 ushort* __restrict__ ctx)
{
    __shared__ __align__(16) ushort sm[13824];
    ushort* Ks = sm;                   // [64 keys][72]
    ushort* Vs = sm + 4608;            // [64 dims][72]
    const int tid = threadIdx.x;
    const int lane = tid & 63, w = tid >> 6;
    const int ln15 = lane & 15, quad = lane >> 4;
    ushort* Ps = sm + 9216 + w * 1152; // per-wave [16 q][72]
    const int bid = blockIdx.x;
    const int qt = bid & 31, bh = bid >> 5;
    const int h = bh & (NHEADS - 1), b = bh >> 4, hkv = h >> 2;
    const int q0 = qt * 64;
    const int qw = q0 + w * 16;

    const ushort* Qrow = Qb + ((size_t)bh * SLEN + qw) * 64;
    const ushort* Kbase = Kg + (size_t)(b * NKV + hkv) * SLEN * 64;
    const ushort* Vbase = Vtg + (size_t)(b * NKV + hkv) * 64 * SLEN;

    short8 qf0 = *reinterpret_cast<const short8*>(Qrow + (size_t)ln15 * 64 + quad * 8);
    short8 qf1 = *reinterpret_cast<const short8*>(Qrow + (size_t)ln15 * 64 + 32 + quad * 8);

    floatx4 O0 = {0,0,0,0}, O1 = {0,0,0,0}, O2 = {0,0,0,0}, O3 = {0,0,0,0};
    float lp[4] = {0.f, 0.f, 0.f, 0.f};

    int kminA = q0 - (WINDOW - 1); if (kminA < 0) kminA = 0;
    kminA &= ~63;
    const int gmax = kminA < NGLOBAL ? kminA : NGLOBAL;
    const int nc = (q0 + 64 - kminA) >> 6;

    for (int c = (gmax > 0 ? -1 : 0); c < nc; ++c) {
        const int kbase = (c < 0) ? 0 : kminA + c * 64;
        __syncthreads();
#pragma unroll
        for (int i = 0; i < 3; ++i) {             // K: 64 rows -> 9 async calls
            const int call = i * 4 + w;
            if (call < 9) stage_row(Kbase + (size_t)kbase * 64, 64, 0, Ks, call, lane);
        }
#pragma unroll
        for (int i = 0; i < 3; ++i) {             // V^T: 64 rows -> 9 async calls
            const int call = i * 4 + w;
            if (call < 9) stage_row(Vbase + kbase, SLEN, 0, Vs, call, lane);
        }
        __syncthreads();

        const bool allvalid = (c >= 0) && (kbase + 63 <= qw) && (kbase + WINDOW >= qw + 16);
        if (allvalid) {
#pragma unroll
            for (int t = 0; t < 4; ++t) {
                short8 kf0 = *reinterpret_cast<const short8*>(&Ks[(t * 16 + ln15) * 72 + quad * 8]);
                short8 kf1 = *reinterpret_cast<const short8*>(&Ks[(t * 16 + ln15) * 72 + 32 + quad * 8]);
                floatx4 sc = {0,0,0,0};
                sc = __builtin_amdgcn_mfma_f32_16x16x32_bf16(qf0, kf0, sc, 0, 0, 0);
                sc = __builtin_amdgcn_mfma_f32_16x16x32_bf16(qf1, kf1, sc, 0, 0, 0);
#pragma unroll
                for (int r = 0; r < 4; ++r) {
                    float sv = sc[r] * 0.125f;
                    float st = sv - sv * sv * sv * (1.0f / 675.0f);
                    float p = __expf(st);
                    Ps[(quad * 4 + r) * 72 + t * 16 + ln15] = f2bf(p);
                    lp[r] += p;
                }
            }
        } else {
#pragma unroll
            for (int t = 0; t < 4; ++t) {
                short8 kf0 = *reinterpret_cast<const short8*>(&Ks[(t * 16 + ln15) * 72 + quad * 8]);
                short8 kf1 = *reinterpret_cast<const short8*>(&Ks[(t * 16 + ln15) * 72 + 32 + quad * 8]);
                floatx4 sc = {0,0,0,0};
                sc = __builtin_amdgcn_mfma_f32_16x16x32_bf16(qf0, kf0, sc, 0, 0, 0);
                sc = __builtin_amdgcn_mfma_f32_16x16x32_bf16(qf1, kf1, sc, 0, 0, 0);
                const int k = kbase + t * 16 + ln15;
#pragma unroll
                for (int r = 0; r < 4; ++r) {
                    const int q = qw + quad * 4 + r;
                    const bool valid = (c < 0) ? (k < gmax)
                                               : (k <= q && (k + WINDOW > q || k < NGLOBAL));
                    float sv = sc[r] * 0.125f;
                    float st = sv - sv * sv * sv * (1.0f / 675.0f);
                    float p = __expf(st);
                    Ps[(quad * 4 + r) * 72 + t * 16 + ln15] = valid ? f2bf(p) : (ushort)0;
                    lp[r] += valid ? p : 0.f;
                }
            }
        }
        short8 af0 = *reinterpret_cast<const short8*>(&Ps[ln15 * 72 + quad * 8]);
        short8 af1 = *reinterpret_cast<const short8*>(&Ps[ln15 * 72 + 32 + quad * 8]);
#pragma unroll
        for (int n = 0; n < 4; ++n) {
            short8 vf0 = *reinterpret_cast<const short8*>(&Vs[(n * 16 + ln15) * 72 + quad * 8]);
            short8 vf1 = *reinterpret_cast<const short8*>(&Vs[(n * 16 + ln15) * 72 + 32 + quad * 8]);
            floatx4 On = (n == 0) ? O0 : (n == 1) ? O1 : (n == 2) ? O2 : O3;
            On = __builtin_amdgcn_mfma_f32_16x16x32_bf16(af0, vf0, On, 0, 0, 0);
            On = __builtin_amdgcn_mfma_f32_16x16x32_bf16(af1, vf1, On, 0, 0, 0);
            if (n == 0) O0 = On; else if (n == 1) O1 = On; else if (n == 2) O2 = On; else O3 = On;
        }
    }

#pragma unroll
    for (int r = 0; r < 4; ++r) {
#pragma unroll
        for (int off = 1; off < 16; off <<= 1)
            lp[r] += __shfl_xor(lp[r], off, 64);
        const float inv = __builtin_amdgcn_rcpf(lp[r]);
        const int q = qw + quad * 4 + r;
        ushort* crow = ctx + ((size_t)(b * SLEN + q)) * DMODEL + h * 64 + ln15;
        crow[0]  = f2bf(O0[r] * inv);
        crow[16] = f2bf(O1[r] * inv);
        crow[32] = f2bf(O2[r] * inv);
        crow[48] = f2bf(O3[r] * inv);
    }
}

// ---------------- out-proj GEMM: 128M x 64N tile, prep-fed K-major Wot ----------------
__global__ __launch_bounds__(256) void gemm_out(const ushort* __restrict__ A,
                                                const ushort* __restrict__ Bt,
                                                void* __restrict__ out,
                                                const uint* __restrict__ cosu)
{
    __shared__ __align__(16) ushort sm[13824];
    ushort* lsA = sm;            // 128 x 72
    ushort* lsB = sm + 9216;     // 64 x 72
    const int tid = threadIdx.x;
    const int lane = tid & 63, w = tid >> 6;
    const int ln15 = lane & 15, quad = lane >> 4;
    const int rm = blockIdx.y * 128;
    const int cn = blockIdx.x * 64;

    floatx4 acc[2][4];
#pragma unroll
    for (int i = 0; i < 2; ++i)
#pragma unroll
        for (int j = 0; j < 4; ++j) acc[i][j] = (floatx4){0.f, 0.f, 0.f, 0.f};

    const ushort* Ab = A + (size_t)rm * 1024;
    const ushort* Bb = Bt + (size_t)cn * 1024;

    for (int k0 = 0; k0 < 1024; k0 += 64) {
        __syncthreads();
#pragma unroll
        for (int i = 0; i < 5; ++i) {
            const int call = i * 4 + w;
            if (call < 18) stage_row(Ab, 1024, k0, lsA, call, lane);
        }
#pragma unroll
        for (int i = 0; i < 3; ++i) {
            const int call = i * 4 + w;
            if (call < 9) stage_row(Bb, 1024, k0, lsB, call, lane);
        }
        __syncthreads();
#pragma unroll
        for (int kk = 0; kk < 64; kk += 32) {
            short8 af[2], bv[4];
#pragma unroll
            for (int i = 0; i < 2; ++i)
                af[i] = *reinterpret_cast<const short8*>(&lsA[(w * 32 + i * 16 + ln15) * 72 + kk + quad * 8]);
#pragma unroll
            for (int j = 0; j < 4; ++j)
                bv[j] = *reinterpret_cast<const short8*>(&lsB[(j * 16 + ln15) * 72 + kk + quad * 8]);
#pragma unroll
            for (int i = 0; i < 2; ++i)
#pragma unroll
                for (int j = 0; j < 4; ++j)
                    acc[i][j] = __builtin_amdgcn_mfma_f32_16x16x32_bf16(af[i], bv[j], acc[i][j], 0, 0, 0);
        }
    }

    const bool outbf = is_bf16_inputs(cosu);
#pragma unroll
    for (int i = 0; i < 2; ++i) {
#pragma unroll
        for (int r = 0; r < 4; ++r) {
            const int grow = rm + w * 32 + i * 16 + quad * 4 + r;
#pragma unroll
            for (int j = 0; j < 4; ++j) {
                const int gcol = cn + j * 16 + ln15;
                if (outbf) reinterpret_cast<ushort*>(out)[(size_t)grow * DMODEL + gcol] = f2bf(acc[i][j][r]);
                else       reinterpret_cast<float*>(out)[(size_t)grow * DMODEL + gcol] = acc[i][j][r];
            }
        }
    }
}

// ---------------- launch: 4 dispatches ----------------
extern "C" void kernel_launch(void* const* d_in, const int* in_sizes, int n_in,
                              void* d_out, int out_size, void* d_ws, size_t ws_size,
                              hipStream_t stream)
{
    (void)in_sizes; (void)n_in; (void)out_size; (void)ws_size;
    const void* x = d_in[0];
    const void* cosi = d_in[1];
    const void* sini = d_in[2];
    const uint* cosu = (const uint*)d_in[1];
    // d_in[3] = mask: computed analytically, not read
    const void* Wq = d_in[4];
    const void* Wk = d_in[5];
    const void* Wv = d_in[6];
    const void* Wo = d_in[7];

    // workspace (~34 MB)
    ushort* xb = (ushort*)d_ws;                        // [4096][1024] bf16 (f32-input case only)
    ushort* Wt = xb + (size_t)4096 * 1024;             // [1536][1024] bf16 (Wq^T|Wk^T|Wv^T)
    ushort* Wot = Wt + (size_t)1536 * 1024;            // [1024][1024] bf16
    float* cosf = (float*)(Wot + (size_t)1024 * 1024); // [2048*32] f32
    float* sinf = cosf + (size_t)SLEN * 32;
    ushort* Qbf = (ushort*)(sinf + (size_t)SLEN * 32); // [2*16*2048][64]
    ushort* Kgf = Qbf + (size_t)BATCH * NHEADS * SLEN * 64;    // [2*4*2048][64]
    ushort* Vtg = Kgf + (size_t)BATCH * NKV * SLEN * 64;       // [2*4][64][2048]
    ushort* ctx = Vtg + (size_t)BATCH * NKV * 64 * SLEN;       // [4096][1024]

    // 1) canonicalization (f32 path) + coalesced weight transposes
    prep_all<<<dim3(5120), 256, 0, stream>>>(x, cosi, sini, Wq, Wk, Wv, Wo,
                                             xb, cosf, sinf, Wt, Wot, cosu);

    // 2) QKV projection + fused l2norm/RoPE/relayout (768 blocks)
    gemm_qkv_nr<<<dim3(24, 32), 256, 0, stream>>>(x, xb, Wt, cosf, sinf,
                                                  Qbf, Kgf, Vtg, cosu);

    // 3) MFMA windowed attention (1024 blocks)
    attn_mfma<<<dim3(BATCH * NHEADS * SLEN / 64), 256, 0, stream>>>(Qbf, Kgf, Vtg, ctx);

    // 4) output projection -> d_out (512 blocks, dtype-matched)
    gemm_out<<<dim3(16, 32), 256, 0, stream>>>(ctx, Wot, d_out, cosu);
}